// Round 1
// baseline (115.036 us; speedup 1.0000x reference)
//
#include <hip/hip_runtime.h>

// LDDMM variational evolve: B=1, N=8192, D=3, fp32.
// dmom_i = 2g * (x_i * sum_j w_ij  -  sum_j w_ij x_j),  w_ij = K_ij <p_i,p_j>
// dx_i   = sum_j K_ij p_j,   K_ij = exp(-g |x_i - x_j|^2), g = 100.
//
// Round 4: j-side operands are wave-uniform -> move them from LDS to SGPRs.
// A prep kernel packs {SB*x_j, SB*y_j, SB*z_j, SC*|x_j|^2} and {p_j} into an
// interleaved float4 array; kernel A reads it with uniform indices so hipcc
// emits s_load_dwordx4/x8 (scalar cache, lgkm prefetchable, zero VGPR cost,
// SALU addressing). No LDS, no __syncthreads. SEG 64->128 gives 2048 blocks
// (8/CU); launch_bounds(256,6) targets >=6 waves/SIMD.
// NOTE: ci must stay inside the exponent (arg <= 0 always); factoring
// exp2(ci) out overflows: inner arg reaches +432 -> inf * 0 = NaN.

#define TPB 256
#define ITILE 2
constexpr float GAMMA_C = 100.0f;
constexpr float LOG2E_C = 1.4426950408889634f;
constexpr float SB_C    = 2.0f * GAMMA_C * LOG2E_C;  // A.xyz = SB*x_j
constexpr float SC_C    = -GAMMA_C * LOG2E_C;        // A.w   = SC*|x_j|^2
constexpr float LN2_C   = 0.69314718055994531f;      // 2g/SB

// ---- Kernel 0: pack j-side operands ---------------------------------------
// J[2*j]   = {SB*x, SB*y, SB*z, SC*|x|^2}
// J[2*j+1] = {px, py, pz, 0}
__global__ __launch_bounds__(TPB) void lddmm_prep(
    const float* __restrict__ mom, const float* __restrict__ xpt,
    float4* __restrict__ J, int N) {
  const int i = blockIdx.x * TPB + threadIdx.x;
  if (i >= N) return;
  const float bx = xpt[3*i], by = xpt[3*i+1], bz = xpt[3*i+2];
  J[2*i]   = make_float4(SB_C*bx, SB_C*by, SB_C*bz,
                         SC_C * fmaf(bx, bx, fmaf(by, by, bz*bz)));
  J[2*i+1] = make_float4(mom[3*i], mom[3*i+1], mom[3*i+2], 0.f);
}

// ---- Kernel A: per-segment partial sums ------------------------------------
// grid (N/(TPB*ITILE), SEG). part layout: P[c][s][i], c=0..6, each [SEG][N].
// j-data comes in via uniform (scalar) loads; each VALU op uses <=1 SGPR
// operand (ISA limit), which every fma below respects.
__global__ __launch_bounds__(TPB, 6) void lddmm_partial(
    const float* __restrict__ mom, const float* __restrict__ xpt,
    const float4* __restrict__ J,
    float* __restrict__ part, int N, int SEG, int JT) {
  const int tid = threadIdx.x;
  const int seg = blockIdx.y;

  const int i0 = blockIdx.x * (TPB * ITILE) + tid;
  const int i1 = i0 + TPB;

  const float x0 = xpt[3*i0], y0 = xpt[3*i0+1], z0 = xpt[3*i0+2];
  const float p0x = mom[3*i0], p0y = mom[3*i0+1], p0z = mom[3*i0+2];
  const float c0 = SC_C * fmaf(x0, x0, fmaf(y0, y0, z0*z0));
  const float x1 = xpt[3*i1], y1 = xpt[3*i1+1], z1 = xpt[3*i1+2];
  const float p1x = mom[3*i1], p1y = mom[3*i1+1], p1z = mom[3*i1+2];
  const float c1 = SC_C * fmaf(x1, x1, fmaf(y1, y1, z1*z1));

  // uniform base: all lanes (and the whole wave) share this pointer
  const float4* __restrict__ Jseg = J + (size_t)2 * (size_t)seg * (size_t)JT;

  float a0=0.f, wx0=0.f, wy0=0.f, wz0=0.f, gx0=0.f, gy0=0.f, gz0=0.f;
  float a1=0.f, wx1=0.f, wy1=0.f, wz1=0.f, gx1=0.f, gy1=0.f, gz1=0.f;

#pragma unroll 4
  for (int t = 0; t < JT; ++t) {
    const float4 A = Jseg[2*t];       // uniform -> s_load_dwordx4
    const float4 P = Jseg[2*t+1];     // uniform -> s_load_dwordx4
    // i0
    {
      const float arg = fmaf(A.x, x0, fmaf(A.y, y0, fmaf(A.z, z0, c0 + A.w)));
      const float K   = __builtin_amdgcn_exp2f(arg);          // bare v_exp_f32
      const float dot = fmaf(P.x, p0x, fmaf(P.y, p0y, P.z * p0z));
      const float w   = K * dot;
      a0 += w;
      wx0 = fmaf(w, A.x, wx0); wy0 = fmaf(w, A.y, wy0); wz0 = fmaf(w, A.z, wz0);
      gx0 = fmaf(K, P.x, gx0); gy0 = fmaf(K, P.y, gy0); gz0 = fmaf(K, P.z, gz0);
    }
    // i1
    {
      const float arg = fmaf(A.x, x1, fmaf(A.y, y1, fmaf(A.z, z1, c1 + A.w)));
      const float K   = __builtin_amdgcn_exp2f(arg);
      const float dot = fmaf(P.x, p1x, fmaf(P.y, p1y, P.z * p1z));
      const float w   = K * dot;
      a1 += w;
      wx1 = fmaf(w, A.x, wx1); wy1 = fmaf(w, A.y, wy1); wz1 = fmaf(w, A.z, wz1);
      gx1 = fmaf(K, P.x, gx1); gy1 = fmaf(K, P.y, gy1); gz1 = fmaf(K, P.z, gz1);
    }
  }

  const size_t SN = (size_t)SEG * N;
  float* p = part + (size_t)seg * N;
  p[0*SN+i0] = a0;  p[0*SN+i1] = a1;
  p[1*SN+i0] = wx0; p[1*SN+i1] = wx1;
  p[2*SN+i0] = wy0; p[2*SN+i1] = wy1;
  p[3*SN+i0] = wz0; p[3*SN+i1] = wz1;
  p[4*SN+i0] = gx0; p[4*SN+i1] = gx1;
  p[5*SN+i0] = gy0; p[5*SN+i1] = gy1;
  p[6*SN+i0] = gz0; p[6*SN+i1] = gz1;
}

// ---- Kernel B: reduce over segments + finalize -----------------------------
__global__ __launch_bounds__(TPB) void lddmm_reduce_fin(
    const float* __restrict__ part, const float* __restrict__ xpt,
    float* __restrict__ out, int N, int SEG) {
  const int i = blockIdx.x * TPB + threadIdx.x;
  const size_t SN = (size_t)SEG * N;
  float acc[7];
#pragma unroll
  for (int c = 0; c < 7; ++c) acc[c] = 0.f;
#pragma unroll 2
  for (int s = 0; s < SEG; ++s) {
    const float* p = part + (size_t)s * N + i;
#pragma unroll
    for (int c = 0; c < 7; ++c) acc[c] += p[(size_t)c * SN];
  }
  const float A  = acc[0];
  const float WX = acc[1], WY = acc[2], WZ = acc[3];
  const float GX = acc[4], GY = acc[5], GZ = acc[6];
  const float xi = xpt[3*i], yi = xpt[3*i+1], zi = xpt[3*i+2];
  const float TGA = 2.0f * GAMMA_C * A;
  out[3*i+0] = fmaf(TGA, xi, -LN2_C * WX);
  out[3*i+1] = fmaf(TGA, yi, -LN2_C * WY);
  out[3*i+2] = fmaf(TGA, zi, -LN2_C * WZ);
  out[3*N + 3*i + 0] = GX;
  out[3*N + 3*i + 1] = GY;
  out[3*N + 3*i + 2] = GZ;
}

// ---- Fallback (tiny ws): atomic single-kernel version ----------------------
__global__ __launch_bounds__(TPB) void lddmm_atomic(
    const float* __restrict__ mom, const float* __restrict__ xpt,
    float* __restrict__ out, int N) {
  const int i  = blockIdx.x * TPB + threadIdx.x;
  const int jb = blockIdx.y * TPB;
  __shared__ float4 sA[TPB], sP[TPB];
  {
    const int j = jb + threadIdx.x;
    const float bx = xpt[3*j], by = xpt[3*j+1], bz = xpt[3*j+2];
    sA[threadIdx.x] = make_float4(SB_C*bx, SB_C*by, SB_C*bz,
                                  SC_C * fmaf(bx, bx, fmaf(by, by, bz*bz)));
    sP[threadIdx.x] = make_float4(mom[3*j], mom[3*j+1], mom[3*j+2], 0.f);
  }
  __syncthreads();
  const float xi = xpt[3*i], yi = xpt[3*i+1], zi = xpt[3*i+2];
  const float pxi = mom[3*i], pyi = mom[3*i+1], pzi = mom[3*i+2];
  const float ci = SC_C * fmaf(xi, xi, fmaf(yi, yi, zi*zi));
  float a=0.f, wx=0.f, wy=0.f, wz=0.f, gx=0.f, gy=0.f, gz=0.f;
#pragma unroll 4
  for (int t = 0; t < TPB; ++t) {
    const float4 A = sA[t], P = sP[t];
    const float arg = fmaf(A.x, xi, fmaf(A.y, yi, fmaf(A.z, zi, ci + A.w)));
    const float K   = __builtin_amdgcn_exp2f(arg);
    const float dot = fmaf(P.x, pxi, fmaf(P.y, pyi, P.z * pzi));
    const float w   = K * dot;
    a += w;
    wx = fmaf(w, A.x, wx); wy = fmaf(w, A.y, wy); wz = fmaf(w, A.z, wz);
    gx = fmaf(K, P.x, gx); gy = fmaf(K, P.y, gy); gz = fmaf(K, P.z, gz);
  }
  const float TGA = 2.0f * GAMMA_C * a;
  atomicAdd(&out[3*i+0], fmaf(TGA, xi, -LN2_C * wx));
  atomicAdd(&out[3*i+1], fmaf(TGA, yi, -LN2_C * wy));
  atomicAdd(&out[3*i+2], fmaf(TGA, zi, -LN2_C * wz));
  atomicAdd(&out[3*N+3*i+0], gx);
  atomicAdd(&out[3*N+3*i+1], gy);
  atomicAdd(&out[3*N+3*i+2], gz);
}

extern "C" void kernel_launch(void* const* d_in, const int* in_sizes, int n_in,
                              void* d_out, int out_size, void* d_ws, size_t ws_size,
                              hipStream_t stream) {
  const float* mom = (const float*)d_in[0];   // setup_inputs order: mom first
  const float* xpt = (const float*)d_in[1];   // control_points second
  float* out = (float*)d_out;
  const int N = in_sizes[0] / 3;              // 8192

  // ws layout: J (8N floats, float4-interleaved) | part (7*SEG*N floats)
  auto need = [&](int s) { return (size_t)(8 + 7*s) * (size_t)N * sizeof(float); };
  int SEG = 128;
  while (SEG > 2 && need(SEG) > ws_size) SEG >>= 1;

  const bool shapes_ok = (N % (TPB * ITILE) == 0) && (N % SEG == 0);
  if (need(SEG) <= ws_size && shapes_ok) {
    const int JT = N / SEG;                   // 64 @ SEG=128
    float4* Jv  = (float4*)d_ws;
    float* partb = (float*)d_ws + (size_t)8 * N;
    lddmm_prep<<<(N + TPB - 1) / TPB, TPB, 0, stream>>>(mom, xpt, Jv, N);
    dim3 gA(N / (TPB * ITILE), SEG);          // (16, 128) = 2048 blocks, 8/CU
    lddmm_partial<<<gA, TPB, 0, stream>>>(mom, xpt, Jv, partb, N, SEG, JT);
    lddmm_reduce_fin<<<N / TPB, TPB, 0, stream>>>(partb, xpt, out, N, SEG);
  } else {
    hipMemsetAsync(d_out, 0, (size_t)out_size * sizeof(float), stream);
    dim3 grid(N / TPB, N / TPB);
    lddmm_atomic<<<grid, TPB, 0, stream>>>(mom, xpt, out, N);
  }
}

// Round 2
// 99.542 us; speedup vs baseline: 1.1557x; 1.1557x over previous
//
#include <hip/hip_runtime.h>

// LDDMM variational evolve: B=1, N=8192, D=3, fp32.
// dmom_i = 2g * (x_i * sum_j w_ij  -  sum_j w_ij x_j),  w_ij = K_ij <p_i,p_j>
// dx_i   = sum_j K_ij p_j,   K_ij = exp(-g |x_i - x_j|^2), g = 100.
//
// Round 5: back to LDS-broadcast staging (r1's uniform-load experiment was
// neutral on partial and its 32-block merged reduce was BW-starved: 29.4 MB
// over 32 CUs at ~25 GB/s/CU ~= 35 us). Changes vs r0 baseline:
//   - ITILE 2->4: 4 independent exp->fma chains per lane (hide v_exp latency),
//     2 ds_read_b128 amortized over 4 pairs (60 VALU instrs per LDS pair).
//   - SEG 64->128 keeps grid at (8,128)=1024 blocks = 4 blocks/CU.
//   - reduce restored to parallel grid (N/TPB, 7) = 224 blocks (~1/CU),
//     separate tiny finalize.
// NOTE: ci must stay inside the exponent (arg <= 0 always); factoring
// exp2(ci) out overflows: inner arg reaches +432 -> inf * 0 = NaN.

#define TPB 256
#define ITILE 4
constexpr float GAMMA_C = 100.0f;
constexpr float LOG2E_C = 1.4426950408889634f;
constexpr float SB_C    = 2.0f * GAMMA_C * LOG2E_C;  // A.xyz = SB*x_j
constexpr float SC_C    = -GAMMA_C * LOG2E_C;        // A.w   = SC*|x_j|^2
constexpr float LN2_C   = 0.69314718055994531f;      // 2g/SB

// ---- Kernel A: per-segment partial sums ------------------------------------
// grid (N/(TPB*ITILE), SEG). part layout: P[c][s][i], c=0..6, each [SEG][N].
__global__ __launch_bounds__(TPB, 4) void lddmm_partial(
    const float* __restrict__ mom, const float* __restrict__ xpt,
    float* __restrict__ part, int N, int SEG, int JT) {
  extern __shared__ float4 smem[];
  float4* sA = smem;        // {SB*x, SB*y, SB*z, SC*|x|^2}
  float4* sP = smem + JT;   // {px, py, pz, 0}
  const int tid = threadIdx.x;
  const int seg = blockIdx.y;

  for (int t = tid; t < JT; t += TPB) {
    const int j = seg * JT + t;
    const float bx = xpt[3*j], by = xpt[3*j+1], bz = xpt[3*j+2];
    sA[t] = make_float4(SB_C*bx, SB_C*by, SB_C*bz,
                        SC_C * fmaf(bx, bx, fmaf(by, by, bz*bz)));
    sP[t] = make_float4(mom[3*j], mom[3*j+1], mom[3*j+2], 0.f);
  }
  __syncthreads();

  const int i0 = blockIdx.x * (TPB * ITILE) + tid;

  float xi[ITILE], yi[ITILE], zi[ITILE];
  float px[ITILE], py[ITILE], pz[ITILE], ci[ITILE];
#pragma unroll
  for (int u = 0; u < ITILE; ++u) {
    const int i = i0 + u * TPB;
    xi[u] = xpt[3*i]; yi[u] = xpt[3*i+1]; zi[u] = xpt[3*i+2];
    px[u] = mom[3*i]; py[u] = mom[3*i+1]; pz[u] = mom[3*i+2];
    ci[u] = SC_C * fmaf(xi[u], xi[u], fmaf(yi[u], yi[u], zi[u]*zi[u]));
  }

  float a[ITILE], wx[ITILE], wy[ITILE], wz[ITILE];
  float gx[ITILE], gy[ITILE], gz[ITILE];
#pragma unroll
  for (int u = 0; u < ITILE; ++u) {
    a[u]=0.f; wx[u]=0.f; wy[u]=0.f; wz[u]=0.f;
    gx[u]=0.f; gy[u]=0.f; gz[u]=0.f;
  }

#pragma unroll 2
  for (int t = 0; t < JT; ++t) {
    const float4 A = sA[t];   // broadcast (same addr all lanes): conflict-free
    const float4 P = sP[t];
#pragma unroll
    for (int u = 0; u < ITILE; ++u) {
      const float arg = fmaf(A.x, xi[u],
                        fmaf(A.y, yi[u],
                        fmaf(A.z, zi[u], ci[u] + A.w)));
      const float K   = __builtin_amdgcn_exp2f(arg);   // bare v_exp_f32
      const float dot = fmaf(P.x, px[u], fmaf(P.y, py[u], P.z * pz[u]));
      const float w   = K * dot;
      a[u] += w;
      wx[u] = fmaf(w, A.x, wx[u]);
      wy[u] = fmaf(w, A.y, wy[u]);
      wz[u] = fmaf(w, A.z, wz[u]);
      gx[u] = fmaf(K, P.x, gx[u]);
      gy[u] = fmaf(K, P.y, gy[u]);
      gz[u] = fmaf(K, P.z, gz[u]);
    }
  }

  const size_t SN = (size_t)SEG * N;
  float* p = part + (size_t)seg * N;
#pragma unroll
  for (int u = 0; u < ITILE; ++u) {
    const int i = i0 + u * TPB;
    p[0*SN+i] = a[u];
    p[1*SN+i] = wx[u];
    p[2*SN+i] = wy[u];
    p[3*SN+i] = wz[u];
    p[4*SN+i] = gx[u];
    p[5*SN+i] = gy[u];
    p[6*SN+i] = gz[u];
  }
}

// ---- Kernel B: reduce over segments (parallel over channels) ---------------
__global__ __launch_bounds__(TPB) void lddmm_reduce(
    const float* __restrict__ part, float* __restrict__ R, int N, int SEG) {
  const int i = blockIdx.x * TPB + threadIdx.x;
  const int c = blockIdx.y;
  const float* src = part + (size_t)c * SEG * N + i;
  float s0 = 0.f, s1 = 0.f, s2 = 0.f, s3 = 0.f;
  int s = 0;
  for (; s + 4 <= SEG; s += 4) {
    s0 += src[(size_t)(s+0)*N]; s1 += src[(size_t)(s+1)*N];
    s2 += src[(size_t)(s+2)*N]; s3 += src[(size_t)(s+3)*N];
  }
  for (; s < SEG; ++s) s0 += src[(size_t)s*N];
  R[(size_t)c * N + i] = (s0 + s1) + (s2 + s3);
}

// ---- Kernel C: finalize ----------------------------------------------------
__global__ __launch_bounds__(TPB) void lddmm_finalize(
    const float* __restrict__ R, const float* __restrict__ xpt,
    float* __restrict__ out, int N) {
  const int i = blockIdx.x * TPB + threadIdx.x;
  const float A  = R[i];
  const float WX = R[(size_t)1*N+i], WY = R[(size_t)2*N+i], WZ = R[(size_t)3*N+i];
  const float GX = R[(size_t)4*N+i], GY = R[(size_t)5*N+i], GZ = R[(size_t)6*N+i];
  const float xi = xpt[3*i], yi = xpt[3*i+1], zi = xpt[3*i+2];
  const float TGA = 2.0f * GAMMA_C * A;
  out[3*i+0] = fmaf(TGA, xi, -LN2_C * WX);
  out[3*i+1] = fmaf(TGA, yi, -LN2_C * WY);
  out[3*i+2] = fmaf(TGA, zi, -LN2_C * WZ);
  out[3*N + 3*i + 0] = GX;
  out[3*N + 3*i + 1] = GY;
  out[3*N + 3*i + 2] = GZ;
}

// ---- Fallback (tiny ws): atomic single-kernel version ----------------------
__global__ __launch_bounds__(TPB) void lddmm_atomic(
    const float* __restrict__ mom, const float* __restrict__ xpt,
    float* __restrict__ out, int N) {
  const int i  = blockIdx.x * TPB + threadIdx.x;
  const int jb = blockIdx.y * TPB;
  __shared__ float4 sA[TPB], sP[TPB];
  {
    const int j = jb + threadIdx.x;
    const float bx = xpt[3*j], by = xpt[3*j+1], bz = xpt[3*j+2];
    sA[threadIdx.x] = make_float4(SB_C*bx, SB_C*by, SB_C*bz,
                                  SC_C * fmaf(bx, bx, fmaf(by, by, bz*bz)));
    sP[threadIdx.x] = make_float4(mom[3*j], mom[3*j+1], mom[3*j+2], 0.f);
  }
  __syncthreads();
  const float xi = xpt[3*i], yi = xpt[3*i+1], zi = xpt[3*i+2];
  const float pxi = mom[3*i], pyi = mom[3*i+1], pzi = mom[3*i+2];
  const float ci = SC_C * fmaf(xi, xi, fmaf(yi, yi, zi*zi));
  float a=0.f, wx=0.f, wy=0.f, wz=0.f, gx=0.f, gy=0.f, gz=0.f;
#pragma unroll 4
  for (int t = 0; t < TPB; ++t) {
    const float4 A = sA[t], P = sP[t];
    const float arg = fmaf(A.x, xi, fmaf(A.y, yi, fmaf(A.z, zi, ci + A.w)));
    const float K   = __builtin_amdgcn_exp2f(arg);
    const float dot = fmaf(P.x, pxi, fmaf(P.y, pyi, P.z * pzi));
    const float w   = K * dot;
    a += w;
    wx = fmaf(w, A.x, wx); wy = fmaf(w, A.y, wy); wz = fmaf(w, A.z, wz);
    gx = fmaf(K, P.x, gx); gy = fmaf(K, P.y, gy); gz = fmaf(K, P.z, gz);
  }
  const float TGA = 2.0f * GAMMA_C * a;
  atomicAdd(&out[3*i+0], fmaf(TGA, xi, -LN2_C * wx));
  atomicAdd(&out[3*i+1], fmaf(TGA, yi, -LN2_C * wy));
  atomicAdd(&out[3*i+2], fmaf(TGA, zi, -LN2_C * wz));
  atomicAdd(&out[3*N+3*i+0], gx);
  atomicAdd(&out[3*N+3*i+1], gy);
  atomicAdd(&out[3*N+3*i+2], gz);
}

extern "C" void kernel_launch(void* const* d_in, const int* in_sizes, int n_in,
                              void* d_out, int out_size, void* d_ws, size_t ws_size,
                              hipStream_t stream) {
  const float* mom = (const float*)d_in[0];   // setup_inputs order: mom first
  const float* xpt = (const float*)d_in[1];   // control_points second
  float* out = (float*)d_out;
  const int N = in_sizes[0] / 3;              // 8192

  // ws layout: part (7*SEG*N floats) | R (7*N floats)
  auto need = [&](int s) { return (size_t)(7*s + 7) * (size_t)N * sizeof(float); };
  int SEG = 128;
  while (SEG > 2 && need(SEG) > ws_size) SEG >>= 1;

  const bool shapes_ok = (N % (TPB * ITILE) == 0) && (N % SEG == 0) &&
                         ((N / SEG) <= TPB);
  if (need(SEG) <= ws_size && shapes_ok) {
    const int JT = N / SEG;                   // 64 @ SEG=128
    float* partb = (float*)d_ws;
    float* R     = partb + (size_t)7 * SEG * N;
    const size_t shmem = (size_t)JT * 2 * sizeof(float4);
    dim3 gA(N / (TPB * ITILE), SEG);          // (8, 128) = 1024 blocks, 4/CU
    lddmm_partial<<<gA, TPB, shmem, stream>>>(mom, xpt, partb, N, SEG, JT);
    dim3 gB(N / TPB, 7);                      // 224 blocks — parallel reduce
    lddmm_reduce<<<gB, TPB, 0, stream>>>(partb, R, N, SEG);
    lddmm_finalize<<<N / TPB, TPB, 0, stream>>>(R, xpt, out, N);
  } else {
    hipMemsetAsync(d_out, 0, (size_t)out_size * sizeof(float), stream);
    dim3 grid(N / TPB, N / TPB);
    lddmm_atomic<<<grid, TPB, 0, stream>>>(mom, xpt, out, N);
  }
}